// Round 7
// baseline (1545.140 us; speedup 1.0000x reference)
//
#include <hip/hip_runtime.h>

#define NBATCH 4
#define NPTS   16384
#define BN     (NBATCH * NPTS)   // 65536 points

typedef __attribute__((ext_vector_type(8))) _Float16 half8;
typedef __attribute__((ext_vector_type(4))) float f32x4;

#define INV4096 2.44140625e-4f

// ---------- split-fp16 (hi + lo*2^-12 ~ fp32 accuracy) ----------
__device__ __forceinline__ void splith(float x, _Float16& h, _Float16& l) {
  float ax = __builtin_fabsf(x);
  if (ax < 6.1035e-5f) {
    unsigned short sb = (unsigned short)((__float_as_uint(x) >> 16) & 0x8000u);
    h = __builtin_bit_cast(_Float16, sb);          // +/-0 preserves sign for relu
    l = (_Float16)(x * 4096.f);
  } else {
    _Float16 hh = (_Float16)x;
    h = hh;
    l = (_Float16)((x - (float)hh) * 4096.f);      // x-hh exact (Sterbenz)
  }
}
__device__ __forceinline__ void splith8(const float v[8], half8& hi, half8& lo) {
  #pragma unroll
  for (int j = 0; j < 8; ++j) { _Float16 h, l; splith(v[j], h, l); hi[j] = h; lo[j] = l; }
}

// zero halves of v where the corresponding half of sgn has its sign bit set
__device__ __forceinline__ half8 relu8(half8 sgn, half8 v) {
  uint4 s = __builtin_bit_cast(uint4, sgn);
  uint4 x = __builtin_bit_cast(uint4, v);
  unsigned* sp = (unsigned*)&s;
  unsigned* xp = (unsigned*)&x;
  uint4 out;
  unsigned* op = (unsigned*)&out;
  #pragma unroll
  for (int w = 0; w < 4; ++w) {
    unsigned m = sp[w] & 0x80008000u;
    unsigned drop = (m - (m >> 15)) | m;   // 0xFFFF per negative half
    op[w] = xp[w] & ~drop;
  }
  return __builtin_bit_cast(half8, out);
}

// ---------- utility kernels ----------
__global__ void k_zero4(float4* __restrict__ p, int n4) {
  int g = blockIdx.x * 256 + threadIdx.x;
  if (g < n4) p[g] = make_float4(0.f, 0.f, 0.f, 0.f);
}

__global__ void k_idx(const float* __restrict__ pts, int* __restrict__ idx,
                      int* __restrict__ cnti) {
  int g = blockIdx.x * 256 + threadIdx.x;
  if (g >= BN) return;
  int b = g >> 14;
  float px = pts[g * 3 + 0], py = pts[g * 3 + 1];
  int xi = (int)(px * 128.f); xi = xi < 0 ? 0 : (xi > 127 ? 127 : xi);
  int yi = (int)(py * 128.f); yi = yi < 0 ? 0 : (yi > 127 ? 127 : yi);
  int id = xi + (yi << 7);
  idx[g] = id;
  atomicAdd(&cnti[(b << 14) + id], 1);
}

// per-batch exclusive scan of cnti -> global sorted offsets (batch base folded in)
__global__ void k_scan(const int* __restrict__ cnti, int* __restrict__ off,
                       int* __restrict__ cursor) {
  __shared__ int part[256];
  const int b = blockIdx.x, t = threadIdx.x;
  const int base = b << 14;
  int s = 0;
  #pragma unroll 8
  for (int i = 0; i < 64; ++i) s += cnti[base + t * 64 + i];
  part[t] = s;
  __syncthreads();
  for (int o = 1; o < 256; o <<= 1) {
    int v = (t >= o) ? part[t - o] : 0;
    __syncthreads();
    part[t] += v;
    __syncthreads();
  }
  int run = base + (t == 0 ? 0 : part[t - 1]);
  #pragma unroll 8
  for (int i = 0; i < 64; ++i) {
    int g = base + t * 64 + i;
    off[g] = run;
    cursor[g] = run;
    run += cnti[g];
  }
}

__global__ void k_scatter(const int* __restrict__ idx, int* __restrict__ cursor,
                          int* __restrict__ perm, int* __restrict__ sbin) {
  int p = blockIdx.x * 256 + threadIdx.x;
  if (p >= BN) return;
  int b = p >> 14;
  int id = idx[p];
  int pos = atomicAdd(&cursor[(b << 14) + id], 1);
  perm[pos] = p;
  sbin[pos] = id;
}

// ---------- pack weights into frag-ordered split-fp16 planes ----------
__device__ __forceinline__ void pack_slot(const float* __restrict__ src, int K,
                                          _Float16* __restrict__ dhi, int NK,
                                          int slot) {
  int fpt = (K >> 5) << 6;
  int t = slot / fpt, rem = slot - t * fpt;
  int s = rem >> 6, lane = rem & 63;
  int row = (t << 4) + (lane & 15);
  int k0 = (s << 5) + ((lane >> 4) << 3);
  float v[8];
  #pragma unroll
  for (int j = 0; j < 8; ++j) v[j] = src[row * K + k0 + j];
  half8 hi, lo; splith8(v, hi, lo);
  *(half8*)&dhi[(size_t)slot << 3] = hi;
  *(half8*)&dhi[((size_t)slot << 3) + NK] = lo;
}

__global__ void k_pack(const float* __restrict__ fc0w, const float* __restrict__ scw,
                       const float* __restrict__ fc1w, const float* __restrict__ fccw,
                       _Float16* __restrict__ wp) {
  int g = blockIdx.x * 256 + threadIdx.x;
  if (g < 20480) {
    int l = g >> 12, slot = g & 4095;
    pack_slot(fc0w + (size_t)l * 32768, 256, wp + (size_t)l * 65536, 32768, slot);
  } else if (g < 40960) {
    int g2 = g - 20480; int l = g2 >> 12, slot = g2 & 4095;
    pack_slot(scw + (size_t)l * 32768, 256, wp + 327680 + (size_t)l * 65536, 32768, slot);
  } else if (g < 51200) {
    int g2 = g - 40960; int l = g2 >> 11, slot = g2 & 2047;
    pack_slot(fc1w + (size_t)l * 16384, 128, wp + 655360 + (size_t)l * 32768, 16384, slot);
  } else {
    int slot = g - 51200;
    pack_slot(fccw, 128, wp + 819200, 16384, slot);
  }
}

// ---------- fused ResnetBlockFC: persistent block, 4 tiles x 32 pts, dbuf LDS ----------
// FUSEC=1 (last layer): also computes cnet = relu(s)@fcc + fccb, stores cnet (=net) only.
template <int SRC, int FUSEC>
__launch_bounds__(256, 2)
__global__ void k_rb(const float* __restrict__ pts, const float* __restrict__ binsIn,
                     const int* __restrict__ perm, const int* __restrict__ sbin,
                     const float* __restrict__ posw, const float* __restrict__ posb,
                     const _Float16* __restrict__ w0p, const float* __restrict__ b0,
                     const _Float16* __restrict__ w1p, const float* __restrict__ b1,
                     const _Float16* __restrict__ wsp,
                     float* __restrict__ net,
                     const _Float16* __restrict__ fccp, const float* __restrict__ fccb,
                     float* __restrict__ cnet) {
  extern __shared__ _Float16 smem[];          // 2 x 16384 halfs = 64 KB
  const int tid = threadIdx.x;
  const int lane = tid & 63, wave = tid >> 6;
  const int pbase = blockIdx.x << 7;          // 128 points per block
  const int b = pbase >> 14;

  const _Float16* w0lo = w0p + 32768;
  const _Float16* wslo = wsp + 32768;
  const _Float16* w1lo = w1p + 16384;

  float pv[4][8];

  // ================= prefetch helper (macro-style via lambda) =================
  auto prefetch = [&](int tt) {
    int p0 = pbase + (tt << 5);
    #pragma unroll
    for (int i = 0; i < 4; ++i) {
      int sidx = tid + (i << 8);
      int m = sidx >> 5, kslot = sidx & 31, k0 = kslot << 3;
      if (SRC == 0) {
        const float* pp = &pts[(size_t)perm[p0 + m] * 3];
        pv[i][0] = pp[0]; pv[i][1] = pp[1]; pv[i][2] = pp[2];
      } else if (kslot < 16) {
        float4 a = *(const float4*)&net[(size_t)(p0 + m) * 128 + k0];
        float4 c = *(const float4*)&net[(size_t)(p0 + m) * 128 + k0 + 4];
        pv[i][0]=a.x; pv[i][1]=a.y; pv[i][2]=a.z; pv[i][3]=a.w;
        pv[i][4]=c.x; pv[i][5]=c.y; pv[i][6]=c.z; pv[i][7]=c.w;
      } else {
        int rb_ = sbin[p0 + m];
        const float* brow = &binsIn[(size_t)(((b << 14) + rb_) << 7) + (k0 - 128)];
        float4 a = *(const float4*)brow;
        float4 c = *(const float4*)(brow + 4);
        pv[i][0]=a.x; pv[i][1]=a.y; pv[i][2]=a.z; pv[i][3]=a.w;
        pv[i][4]=c.x; pv[i][5]=c.y; pv[i][6]=c.z; pv[i][7]=c.w;
      }
    }
  };
  auto commit = [&](int tt) {
    _Float16* Shi = smem + ((tt & 1) << 14);
    _Float16* Slo = Shi + 8192;
    #pragma unroll
    for (int i = 0; i < 4; ++i) {
      int sidx = tid + (i << 8);
      int m = sidx >> 5, kslot = sidx & 31, k0 = kslot << 3;
      float v[8];
      if (SRC == 0) {
        float px = pv[i][0], py = pv[i][1], pz = pv[i][2];
        #pragma unroll
        for (int j = 0; j < 8; ++j) {
          int c = k0 + j;
          v[j] = fmaf(posw[c * 3 + 0], px,
                 fmaf(posw[c * 3 + 1], py,
                 fmaf(posw[c * 3 + 2], pz, posb[c])));
        }
      } else {
        #pragma unroll
        for (int j = 0; j < 8; ++j) v[j] = pv[i][j];
      }
      half8 hi, lo; splith8(v, hi, lo);
      int mt = m >> 4, mm = m & 15, s = kslot >> 2, quad = kslot & 3;
      int ln = mm + (quad << 4), kg = (mt << 3) + s;   // kg in [0,16)
      int u = (kg << 6) + (ln ^ (kg & 7));
      *(half8*)&Shi[u << 3] = hi;
      *(half8*)&Slo[u << 3] = lo;
    }
  };

  // ---- prologue: tile 0 into buffer 0 ----
  prefetch(0);
  commit(0);
  __syncthreads();

  for (int t = 0; t < 4; ++t) {
    _Float16* Shi = smem + ((t & 1) << 14);
    _Float16* Slo = Shi + 8192;
    const int p0 = pbase + (t << 5);

    if (t < 3) prefetch(t + 1);     // loads in flight during GEMMs

    // ---- combined K-loop: h = relu(x)@w0+b0 ; s = x@ws+b1 ----
    f32x4 hm[2][2], hc[2][2], so[2][2], sc[2][2];
    {
      int col = lane & 15;
      #pragma unroll
      for (int nt = 0; nt < 2; ++nt) {
        float bv0 = b0[(wave << 5) + (nt << 4) + col];
        float bv1 = b1[(wave << 5) + (nt << 4) + col];
        #pragma unroll
        for (int mt = 0; mt < 2; ++mt) {
          hm[mt][nt] = (f32x4){bv0, bv0, bv0, bv0};
          so[mt][nt] = (f32x4){bv1, bv1, bv1, bv1};
          hc[mt][nt] = (f32x4){0.f, 0.f, 0.f, 0.f};
          sc[mt][nt] = (f32x4){0.f, 0.f, 0.f, 0.f};
        }
      }
    }
    half8 c0h[2], c0l[2], csh[2], csl[2];
    #pragma unroll
    for (int nt = 0; nt < 2; ++nt) {            // preload ks = 0
      int tw = (wave << 1) + nt;
      size_t fo = (((size_t)(tw << 3) << 6) + lane) << 3;
      c0h[nt] = *(const half8*)&w0p[fo];
      c0l[nt] = *(const half8*)&w0lo[fo];
      csh[nt] = *(const half8*)&wsp[fo];
      csl[nt] = *(const half8*)&wslo[fo];
    }
    for (int ks = 0; ks < 8; ++ks) {
      half8 n0h[2], n0l[2], nsh[2], nsl[2];
      int ksn = (ks + 1) & 7;
      #pragma unroll
      for (int nt = 0; nt < 2; ++nt) {
        int tw = (wave << 1) + nt;
        size_t fo = (((size_t)((tw << 3) + ksn) << 6) + lane) << 3;
        n0h[nt] = *(const half8*)&w0p[fo];
        n0l[nt] = *(const half8*)&w0lo[fo];
        nsh[nt] = *(const half8*)&wsp[fo];
        nsl[nt] = *(const half8*)&wslo[fo];
      }
      #pragma unroll
      for (int mt = 0; mt < 2; ++mt) {
        int kg = (mt << 3) + ks;
        int u = (kg << 6) + (lane ^ (kg & 7));
        half8 ah = *(const half8*)&Shi[u << 3];
        half8 al = *(const half8*)&Slo[u << 3];
        half8 arh = relu8(ah, ah);
        half8 arl = relu8(ah, al);
        #pragma unroll
        for (int nt = 0; nt < 2; ++nt) {
          hm[mt][nt] = __builtin_amdgcn_mfma_f32_16x16x32_f16(arh, c0h[nt], hm[mt][nt], 0, 0, 0);
          hc[mt][nt] = __builtin_amdgcn_mfma_f32_16x16x32_f16(arl, c0h[nt], hc[mt][nt], 0, 0, 0);
          hc[mt][nt] = __builtin_amdgcn_mfma_f32_16x16x32_f16(arh, c0l[nt], hc[mt][nt], 0, 0, 0);
          so[mt][nt] = __builtin_amdgcn_mfma_f32_16x16x32_f16(ah,  csh[nt], so[mt][nt], 0, 0, 0);
          sc[mt][nt] = __builtin_amdgcn_mfma_f32_16x16x32_f16(al,  csh[nt], sc[mt][nt], 0, 0, 0);
          sc[mt][nt] = __builtin_amdgcn_mfma_f32_16x16x32_f16(ah,  csl[nt], sc[mt][nt], 0, 0, 0);
        }
      }
      #pragma unroll
      for (int nt = 0; nt < 2; ++nt) {
        c0h[nt] = n0h[nt]; c0l[nt] = n0l[nt];
        csh[nt] = nsh[nt]; csl[nt] = nsl[nt];
      }
    }
    __syncthreads();   // x(t) fully consumed; overlay A2 on its buffer

    // ---- write relu(h) into A2 frag planes (K2 = 128) ----
    _Float16* A2hi = Shi;
    _Float16* A2lo = Shi + 4096;
    {
      int q = lane >> 4, j2 = lane & 7, qh = (lane & 15) >> 3;
      #pragma unroll
      for (int mt = 0; mt < 2; ++mt) {
        int kg2 = (mt << 2) + wave;             // [0,8)
        #pragma unroll
        for (int nt = 0; nt < 2; ++nt) {
          int quad2 = (nt << 1) + qh;
          #pragma unroll
          for (int r = 0; r < 4; ++r) {
            float hv = fmaxf(fmaf(hc[mt][nt][r], INV4096, hm[mt][nt][r]), 0.f);
            _Float16 hb, lb; splith(hv, hb, lb);
            int mm2 = (q << 2) + r;
            int ln2 = mm2 + (quad2 << 4);
            int u2 = (kg2 << 6) + (ln2 ^ (kg2 & 7));
            A2hi[(u2 << 3) + j2] = hb;
            A2lo[(u2 << 3) + j2] = lb;
          }
        }
      }
    }
    __syncthreads();

    // ---- GEMM1: s += relu(h) @ w1 ----
    half8 w1ch[2], w1cl[2];
    #pragma unroll
    for (int nt = 0; nt < 2; ++nt) {
      int tw = (wave << 1) + nt;
      size_t fo = (((size_t)(tw << 2) << 6) + lane) << 3;
      w1ch[nt] = *(const half8*)&w1p[fo];
      w1cl[nt] = *(const half8*)&w1lo[fo];
    }
    for (int ks = 0; ks < 4; ++ks) {
      half8 nh[2], nl[2];
      int ksn = (ks + 1) & 3;
      #pragma unroll
      for (int nt = 0; nt < 2; ++nt) {
        int tw = (wave << 1) + nt;
        size_t fo = (((size_t)((tw << 2) + ksn) << 6) + lane) << 3;
        nh[nt] = *(const half8*)&w1p[fo];
        nl[nt] = *(const half8*)&w1lo[fo];
      }
      #pragma unroll
      for (int mt = 0; mt < 2; ++mt) {
        int kg = (mt << 2) + ks;
        int u = (kg << 6) + (lane ^ (kg & 7));
        half8 ah = *(const half8*)&A2hi[u << 3];
        half8 al = *(const half8*)&A2lo[u << 3];
        #pragma unroll
        for (int nt = 0; nt < 2; ++nt) {
          so[mt][nt] = __builtin_amdgcn_mfma_f32_16x16x32_f16(ah, w1ch[nt], so[mt][nt], 0, 0, 0);
          sc[mt][nt] = __builtin_amdgcn_mfma_f32_16x16x32_f16(al, w1ch[nt], sc[mt][nt], 0, 0, 0);
          sc[mt][nt] = __builtin_amdgcn_mfma_f32_16x16x32_f16(ah, w1cl[nt], sc[mt][nt], 0, 0, 0);
        }
      }
      #pragma unroll
      for (int nt = 0; nt < 2; ++nt) { w1ch[nt] = nh[nt]; w1cl[nt] = nl[nt]; }
    }

    if (!FUSEC) {
      // ---- epilogue: plain store (sorted rows) ----
      int col = lane & 15, q = lane >> 4;
      #pragma unroll
      for (int mt = 0; mt < 2; ++mt) {
        #pragma unroll
        for (int r = 0; r < 4; ++r) {
          int m_g = p0 + (mt << 4) + (q << 2) + r;
          #pragma unroll
          for (int nt = 0; nt < 2; ++nt) {
            int n = (wave << 5) + (nt << 4) + col;
            net[(size_t)m_g * 128 + n] = fmaf(sc[mt][nt][r], INV4096, so[mt][nt][r]);
          }
        }
      }
    } else {
      // ---- fused fc_c: cnet = relu(s)@fcc + fccb ----
      __syncthreads();   // A2(h) fully read; reuse region for relu(s)
      {
        int q = lane >> 4, j2 = lane & 7, qh = (lane & 15) >> 3;
        #pragma unroll
        for (int mt = 0; mt < 2; ++mt) {
          int kg2 = (mt << 2) + wave;
          #pragma unroll
          for (int nt = 0; nt < 2; ++nt) {
            int quad2 = (nt << 1) + qh;
            #pragma unroll
            for (int r = 0; r < 4; ++r) {
              float sv = fmaxf(fmaf(sc[mt][nt][r], INV4096, so[mt][nt][r]), 0.f);
              _Float16 hb, lb; splith(sv, hb, lb);
              int mm2 = (q << 2) + r;
              int ln2 = mm2 + (quad2 << 4);
              int u2 = (kg2 << 6) + (ln2 ^ (kg2 & 7));
              A2hi[(u2 << 3) + j2] = hb;
              A2lo[(u2 << 3) + j2] = lb;
            }
          }
        }
      }
      __syncthreads();
      const _Float16* flo = fccp + 16384;
      f32x4 am[2][2], ac[2][2];
      {
        int col = lane & 15;
        #pragma unroll
        for (int nt = 0; nt < 2; ++nt) {
          float bv = fccb[(wave << 5) + (nt << 4) + col];
          #pragma unroll
          for (int mt = 0; mt < 2; ++mt) {
            am[mt][nt] = (f32x4){bv, bv, bv, bv};
            ac[mt][nt] = (f32x4){0.f, 0.f, 0.f, 0.f};
          }
        }
      }
      for (int ks = 0; ks < 4; ++ks) {
        half8 ch[2], cl[2];
        #pragma unroll
        for (int nt = 0; nt < 2; ++nt) {
          int tw = (wave << 1) + nt;
          size_t fo = (((size_t)((tw << 2) + ks) << 6) + lane) << 3;
          ch[nt] = *(const half8*)&fccp[fo];
          cl[nt] = *(const half8*)&flo[fo];
        }
        #pragma unroll
        for (int mt = 0; mt < 2; ++mt) {
          int kg = (mt << 2) + ks;
          int u = (kg << 6) + (lane ^ (kg & 7));
          half8 ah = *(const half8*)&A2hi[u << 3];
          half8 al = *(const half8*)&A2lo[u << 3];
          #pragma unroll
          for (int nt = 0; nt < 2; ++nt) {
            am[mt][nt] = __builtin_amdgcn_mfma_f32_16x16x32_f16(ah, ch[nt], am[mt][nt], 0, 0, 0);
            ac[mt][nt] = __builtin_amdgcn_mfma_f32_16x16x32_f16(al, ch[nt], ac[mt][nt], 0, 0, 0);
            ac[mt][nt] = __builtin_amdgcn_mfma_f32_16x16x32_f16(ah, cl[nt], ac[mt][nt], 0, 0, 0);
          }
        }
      }
      int col = lane & 15, q = lane >> 4;
      #pragma unroll
      for (int mt = 0; mt < 2; ++mt) {
        #pragma unroll
        for (int r = 0; r < 4; ++r) {
          int m_g = p0 + (mt << 4) + (q << 2) + r;
          #pragma unroll
          for (int nt = 0; nt < 2; ++nt) {
            int n = (wave << 5) + (nt << 4) + col;
            cnet[(size_t)m_g * 128 + n] = fmaf(ac[mt][nt][r], INV4096, am[mt][nt][r]);
          }
        }
      }
    }

    if (t < 3) commit(t + 1);       // split + LDS write of next tile
    __syncthreads();
  }
}

// ---------- segment max over contiguous sorted rows (one wave per bin) ----------
__launch_bounds__(256)
__global__ void k_seg(const float* __restrict__ net, const int* __restrict__ off,
                      const int* __restrict__ cnti, float* __restrict__ bins) {
  int g = blockIdx.x * 4 + (threadIdx.x >> 6);
  int lane = threadIdx.x & 63;
  int n = cnti[g];
  if (n == 0) return;
  int s = off[g];
  int c2 = lane << 1;
  float2 mx = *(const float2*)&net[(size_t)s * 128 + c2];
  for (int r = 1; r < n; ++r) {
    float2 v = *(const float2*)&net[(size_t)(s + r) * 128 + c2];
    mx.x = fmaxf(mx.x, v.x); mx.y = fmaxf(mx.y, v.y);
  }
  *(float2*)&bins[((size_t)g << 7) + c2] = mx;
}

// ---------- segment sum over contiguous sorted rows (empty bins -> 0) ----------
__launch_bounds__(256)
__global__ void k_segsum(const float* __restrict__ cnet, const int* __restrict__ off,
                         const int* __restrict__ cnti, float* __restrict__ sums) {
  int g = blockIdx.x * 4 + (threadIdx.x >> 6);
  int lane = threadIdx.x & 63;
  int n = cnti[g];
  int c2 = lane << 1;
  float2 acc = make_float2(0.f, 0.f);
  int s = off[g];
  for (int r = 0; r < n; ++r) {
    float2 v = *(const float2*)&cnet[(size_t)(s + r) * 128 + c2];
    acc.x += v.x; acc.y += v.y;
  }
  *(float2*)&sums[((size_t)g << 7) + c2] = acc;
}

// ---------- divide by counts + transpose (B,R2,C) -> (B,C,R2) ----------
__launch_bounds__(256)
__global__ void k_finalize(const float* __restrict__ sums, const int* __restrict__ cnti,
                           float* __restrict__ out) {
  __shared__ float t[64 * 65];
  __shared__ float rc[64];
  const int bid = blockIdx.x;
  const int ct = bid & 1, rt = (bid >> 1) & 255, b = bid >> 9;
  const int r0 = rt << 6, c0 = ct << 6;
  const int tid = threadIdx.x, l16 = tid & 15, sl = tid >> 4;
  for (int rr = sl; rr < 64; rr += 16) {
    float4 v = *(const float4*)&sums[(size_t)((b << 14) + r0 + rr) * 128 + c0 + (l16 << 2)];
    int cb = l16 << 2;
    t[rr * 65 + cb + 0] = v.x; t[rr * 65 + cb + 1] = v.y;
    t[rr * 65 + cb + 2] = v.z; t[rr * 65 + cb + 3] = v.w;
  }
  if (tid < 64) rc[tid] = 1.f / fmaxf((float)cnti[(b << 14) + r0 + tid], 1.f);
  __syncthreads();
  for (int cc = sl; cc < 64; cc += 16) {
    int c = c0 + cc;
    int rb = l16 << 2;
    float4 o = make_float4(t[(rb + 0) * 65 + cc] * rc[rb + 0],
                           t[(rb + 1) * 65 + cc] * rc[rb + 1],
                           t[(rb + 2) * 65 + cc] * rc[rb + 2],
                           t[(rb + 3) * 65 + cc] * rc[rb + 3]);
    *(float4*)&out[(size_t)((b << 7) + c) * 16384 + r0 + rb] = o;
  }
}

// ---------- host launch ----------
extern "C" void kernel_launch(void* const* d_in, const int* in_sizes, int n_in,
                              void* d_out, int out_size, void* d_ws, size_t ws_size,
                              hipStream_t stream) {
  const float* points = (const float*)d_in[0];
  const float* posw   = (const float*)d_in[1];
  const float* posb   = (const float*)d_in[2];
  const float* fc0w   = (const float*)d_in[3];
  const float* fc0b   = (const float*)d_in[4];
  const float* fc1w   = (const float*)d_in[5];
  const float* fc1b   = (const float*)d_in[6];
  const float* scw    = (const float*)d_in[7];
  const float* fccw   = (const float*)d_in[8];
  const float* fccb   = (const float*)d_in[9];
  float* outp = (float*)d_out;

  float* net  = (float*)d_ws;
  float* bins = net + (size_t)BN * 128;
  int* idxp   = (int*)(bins + (size_t)BN * 128);
  int* perm   = idxp + BN;
  int* sbin   = perm + BN;
  int* cnti   = sbin + BN;
  int* off    = cnti + BN;
  int* cursor = off + BN;
  _Float16* wp = (_Float16*)(cursor + BN);

  const _Float16* w0_ = wp;            // 5 x 65536 (hi|lo)
  const _Float16* ws_ = wp + 327680;   // 5 x 65536
  const _Float16* w1_ = wp + 655360;   // 5 x 32768
  const _Float16* fcc_ = wp + 819200;  // 32768

  k_zero4<<<64, 256, 0, stream>>>((float4*)cnti, 16384);
  k_idx<<<256, 256, 0, stream>>>(points, idxp, cnti);
  k_scan<<<4, 256, 0, stream>>>(cnti, off, cursor);
  k_scatter<<<256, 256, 0, stream>>>(idxp, cursor, perm, sbin);
  k_pack<<<208, 256, 0, stream>>>(fc0w, scw, fc1w, fccw, wp);

  // layer 0
  k_rb<0, 0><<<512, 256, 65536, stream>>>(points, bins, perm, sbin, posw, posb,
                                          w0_, fc0b, w1_, fc1b, ws_, net,
                                          fcc_, fccb, net);
  // layers 1..3
  for (int l = 1; l < 4; ++l) {
    k_seg<<<16384, 256, 0, stream>>>(net, off, cnti, bins);
    k_rb<1, 0><<<512, 256, 65536, stream>>>(points, bins, perm, sbin, posw, posb,
                                            w0_ + (size_t)l * 65536, fc0b + l * 128,
                                            w1_ + (size_t)l * 32768, fc1b + l * 128,
                                            ws_ + (size_t)l * 65536, net,
                                            fcc_, fccb, net);
  }
  // layer 4 with fused fc_c: writes cnet in place of net (row-disjoint, safe)
  k_seg<<<16384, 256, 0, stream>>>(net, off, cnti, bins);
  k_rb<1, 1><<<512, 256, 65536, stream>>>(points, bins, perm, sbin, posw, posb,
                                          w0_ + (size_t)4 * 65536, fc0b + 4 * 128,
                                          w1_ + (size_t)4 * 32768, fc1b + 4 * 128,
                                          ws_ + (size_t)4 * 65536, net,
                                          fcc_, fccb, net);
  // segment mean over cnet (= net), sums into bins, finalize
  k_segsum<<<16384, 256, 0, stream>>>(net, off, cnti, bins);
  k_finalize<<<2048, 256, 0, stream>>>(bins, cnti, outp);
}

// Round 8
// 430.599 us; speedup vs baseline: 3.5883x; 3.5883x over previous
//
#include <hip/hip_runtime.h>

#define NBATCH 4
#define NPTS   16384
#define BN     (NBATCH * NPTS)   // 65536 points

typedef __attribute__((ext_vector_type(8))) _Float16 half8;
typedef __attribute__((ext_vector_type(4))) float f32x4;

#define INV4096 2.44140625e-4f

// ---------- order-preserving float<->uint encoding for atomic max ----------
__device__ __forceinline__ unsigned fenc(float f) {
  unsigned u = __float_as_uint(f);
  return (u & 0x80000000u) ? ~u : (u | 0x80000000u);
}
__device__ __forceinline__ float fdec(unsigned u) {
  unsigned b = (u & 0x80000000u) ? (u & 0x7fffffffu) : ~u;
  return __uint_as_float(b);
}

// ---------- split-fp16 (hi + lo*2^-12 ~ fp32 accuracy) ----------
__device__ __forceinline__ void splith(float x, _Float16& h, _Float16& l) {
  float ax = __builtin_fabsf(x);
  if (ax < 6.1035e-5f) {
    unsigned short sb = (unsigned short)((__float_as_uint(x) >> 16) & 0x8000u);
    h = __builtin_bit_cast(_Float16, sb);          // +/-0 preserves sign for relu
    l = (_Float16)(x * 4096.f);
  } else {
    _Float16 hh = (_Float16)x;
    h = hh;
    l = (_Float16)((x - (float)hh) * 4096.f);      // x-hh exact (Sterbenz)
  }
}
__device__ __forceinline__ void splith8(const float v[8], half8& hi, half8& lo) {
  #pragma unroll
  for (int j = 0; j < 8; ++j) { _Float16 h, l; splith(v[j], h, l); hi[j] = h; lo[j] = l; }
}

// zero halves of v where the corresponding half of sgn has its sign bit set
__device__ __forceinline__ half8 relu8(half8 sgn, half8 v) {
  uint4 s = __builtin_bit_cast(uint4, sgn);
  uint4 x = __builtin_bit_cast(uint4, v);
  unsigned* sp = (unsigned*)&s;
  unsigned* xp = (unsigned*)&x;
  uint4 out;
  unsigned* op = (unsigned*)&out;
  #pragma unroll
  for (int w = 0; w < 4; ++w) {
    unsigned m = sp[w] & 0x80008000u;
    unsigned drop = (m - (m >> 15)) | m;   // 0xFFFF per negative half
    op[w] = xp[w] & ~drop;
  }
  return __builtin_bit_cast(half8, out);
}

// ---------- utility kernels ----------
__global__ void k_zero4(float4* __restrict__ p, int n4) {
  int g = blockIdx.x * 256 + threadIdx.x;
  if (g < n4) p[g] = make_float4(0.f, 0.f, 0.f, 0.f);
}

__device__ __forceinline__ int bin_of(const float* __restrict__ pts, int g) {
  float px = pts[g * 3 + 0], py = pts[g * 3 + 1];
  int xi = (int)(px * 128.f); xi = xi < 0 ? 0 : (xi > 127 ? 127 : xi);
  int yi = (int)(py * 128.f); yi = yi < 0 ? 0 : (yi > 127 ? 127 : yi);
  return xi + (yi << 7);
}

__global__ void k_idx(const float* __restrict__ pts, int* __restrict__ cnti) {
  int g = blockIdx.x * 256 + threadIdx.x;
  if (g >= BN) return;
  int b = g >> 14;
  atomicAdd(&cnti[(b << 14) + bin_of(pts, g)], 1);
}

// per-batch exclusive scan of cnti -> cursor (batch base folded in)
__global__ void k_scan(const int* __restrict__ cnti, int* __restrict__ cursor) {
  __shared__ int part[256];
  const int b = blockIdx.x, t = threadIdx.x;
  const int base = b << 14;
  int s = 0;
  #pragma unroll 8
  for (int i = 0; i < 64; ++i) s += cnti[base + t * 64 + i];
  part[t] = s;
  __syncthreads();
  for (int o = 1; o < 256; o <<= 1) {
    int v = (t >= o) ? part[t - o] : 0;
    __syncthreads();
    part[t] += v;
    __syncthreads();
  }
  int run = base + (t == 0 ? 0 : part[t - 1]);
  #pragma unroll 8
  for (int i = 0; i < 64; ++i) {
    int g = base + t * 64 + i;
    cursor[g] = run;
    run += cnti[g];
  }
}

__global__ void k_scatter(const float* __restrict__ pts, int* __restrict__ cursor,
                          int* __restrict__ perm, int* __restrict__ sbin) {
  int p = blockIdx.x * 256 + threadIdx.x;
  if (p >= BN) return;
  int b = p >> 14;
  int id = bin_of(pts, p);
  int pos = atomicAdd(&cursor[(b << 14) + id], 1);
  perm[pos] = p;
  sbin[pos] = id;
}

// ---------- pack weights into frag-ordered split-fp16 planes ----------
__device__ __forceinline__ void pack_slot(const float* __restrict__ src, int K,
                                          _Float16* __restrict__ dhi, int NK,
                                          int slot) {
  int fpt = (K >> 5) << 6;
  int t = slot / fpt, rem = slot - t * fpt;
  int s = rem >> 6, lane = rem & 63;
  int row = (t << 4) + (lane & 15);
  int k0 = (s << 5) + ((lane >> 4) << 3);
  float v[8];
  #pragma unroll
  for (int j = 0; j < 8; ++j) v[j] = src[row * K + k0 + j];
  half8 hi, lo; splith8(v, hi, lo);
  *(half8*)&dhi[(size_t)slot << 3] = hi;
  *(half8*)&dhi[((size_t)slot << 3) + NK] = lo;
}

__global__ void k_pack(const float* __restrict__ fc0w, const float* __restrict__ scw,
                       const float* __restrict__ fc1w, const float* __restrict__ fccw,
                       _Float16* __restrict__ wp) {
  int g = blockIdx.x * 256 + threadIdx.x;
  if (g < 20480) {
    int l = g >> 12, slot = g & 4095;
    pack_slot(fc0w + (size_t)l * 32768, 256, wp + (size_t)l * 65536, 32768, slot);
  } else if (g < 40960) {
    int g2 = g - 20480; int l = g2 >> 12, slot = g2 & 4095;
    pack_slot(scw + (size_t)l * 32768, 256, wp + 327680 + (size_t)l * 65536, 32768, slot);
  } else if (g < 51200) {
    int g2 = g - 40960; int l = g2 >> 11, slot = g2 & 2047;
    pack_slot(fc1w + (size_t)l * 16384, 128, wp + 655360 + (size_t)l * 32768, 16384, slot);
  } else {
    int slot = g - 51200;
    pack_slot(fccw, 128, wp + 819200, 16384, slot);
  }
}

// ---------- fused ResnetBlockFC (MFMA, split-fp16), 32 sorted pts/block ----------
// MODE 0: epilogue = store net + per-block segmented bin-max -> atomicMax(binsOut)
// MODE 1: epilogue = fused fc_c GEMM + per-block segmented bin-sum -> atomicAdd(sums)
template <int SRC, int MODE>
__launch_bounds__(256, 4)
__global__ void k_rb(const float* __restrict__ pts, const unsigned* __restrict__ binsIn,
                     const int* __restrict__ perm, const int* __restrict__ sbin,
                     const float* __restrict__ posw, const float* __restrict__ posb,
                     const _Float16* __restrict__ w0p, const float* __restrict__ b0,
                     const _Float16* __restrict__ w1p, const float* __restrict__ b1,
                     const _Float16* __restrict__ wsp,
                     float* __restrict__ net,
                     unsigned* __restrict__ binsOut,
                     const _Float16* __restrict__ fccp, const float* __restrict__ fccb,
                     float* __restrict__ sums) {
  extern __shared__ _Float16 smem[];          // 32 KB
  _Float16* Ahi = smem;                       // 8192 f16
  _Float16* Alo = smem + 8192;
  const int tid = threadIdx.x;
  const int lane = tid & 63, wave = tid >> 6;
  const int p0 = blockIdx.x << 5;             // 32 sorted points
  const int b = p0 >> 14;

  // ---- stage x (hi/lo frag planes, XOR-swizzled) ----
  #pragma unroll
  for (int i = 0; i < 4; ++i) {
    int sidx = tid + (i << 8);                // 1024 slots
    int m = sidx >> 5, kslot = sidx & 31, k0 = kslot << 3;
    float v[8];
    if (SRC == 0) {
      const float* pp = &pts[(size_t)perm[p0 + m] * 3];
      float px = pp[0], py = pp[1], pz = pp[2];
      #pragma unroll
      for (int j = 0; j < 8; ++j) {
        int c = k0 + j;
        v[j] = fmaf(posw[c * 3 + 0], px,
               fmaf(posw[c * 3 + 1], py,
               fmaf(posw[c * 3 + 2], pz, posb[c])));
      }
    } else {
      if (kslot < 16) {
        float4 a = *(const float4*)&net[(size_t)(p0 + m) * 128 + k0];
        float4 c = *(const float4*)&net[(size_t)(p0 + m) * 128 + k0 + 4];
        v[0] = a.x; v[1] = a.y; v[2] = a.z; v[3] = a.w;
        v[4] = c.x; v[5] = c.y; v[6] = c.z; v[7] = c.w;
      } else {
        int rb_ = sbin[p0 + m];
        const unsigned* brow = &binsIn[(size_t)(((b << 14) + rb_) << 7) + (k0 - 128)];
        uint4 a = *(const uint4*)brow;
        uint4 c = *(const uint4*)(brow + 4);
        v[0] = fdec(a.x); v[1] = fdec(a.y); v[2] = fdec(a.z); v[3] = fdec(a.w);
        v[4] = fdec(c.x); v[5] = fdec(c.y); v[6] = fdec(c.z); v[7] = fdec(c.w);
      }
    }
    half8 hi, lo; splith8(v, hi, lo);
    int mt = m >> 4, mm = m & 15, s = kslot >> 2, quad = kslot & 3;
    int ln = mm + (quad << 4), kg = (mt << 3) + s;   // kg in [0,16)
    int u = (kg << 6) + (ln ^ (kg & 7));
    *(half8*)&Ahi[u << 3] = hi;
    *(half8*)&Alo[u << 3] = lo;
  }
  __syncthreads();

  // ---- combined K-loop: h = relu(x)@w0+b0 ; s = x@ws+b1 (main + cross acc) ----
  f32x4 hm[2][2], hc[2][2], so[2][2], sc[2][2];
  {
    int col = lane & 15;
    #pragma unroll
    for (int nt = 0; nt < 2; ++nt) {
      float bv0 = b0[(wave << 5) + (nt << 4) + col];
      float bv1 = b1[(wave << 5) + (nt << 4) + col];
      #pragma unroll
      for (int mt = 0; mt < 2; ++mt) {
        hm[mt][nt] = (f32x4){bv0, bv0, bv0, bv0};
        so[mt][nt] = (f32x4){bv1, bv1, bv1, bv1};
        hc[mt][nt] = (f32x4){0.f, 0.f, 0.f, 0.f};
        sc[mt][nt] = (f32x4){0.f, 0.f, 0.f, 0.f};
      }
    }
  }
  const _Float16* w0lo = w0p + 32768;
  const _Float16* wslo = wsp + 32768;

  half8 c0h[2], c0l[2], csh[2], csl[2];
  #pragma unroll
  for (int nt = 0; nt < 2; ++nt) {            // preload ks = 0
    int tw = (wave << 1) + nt;
    size_t fo = (((size_t)(tw << 3) << 6) + lane) << 3;
    c0h[nt] = *(const half8*)&w0p[fo];
    c0l[nt] = *(const half8*)&w0lo[fo];
    csh[nt] = *(const half8*)&wsp[fo];
    csl[nt] = *(const half8*)&wslo[fo];
  }
  for (int ks = 0; ks < 8; ++ks) {
    half8 n0h[2], n0l[2], nsh[2], nsl[2];
    int ksn = (ks + 1) & 7;
    #pragma unroll
    for (int nt = 0; nt < 2; ++nt) {
      int tw = (wave << 1) + nt;
      size_t fo = (((size_t)((tw << 3) + ksn) << 6) + lane) << 3;
      n0h[nt] = *(const half8*)&w0p[fo];
      n0l[nt] = *(const half8*)&w0lo[fo];
      nsh[nt] = *(const half8*)&wsp[fo];
      nsl[nt] = *(const half8*)&wslo[fo];
    }
    #pragma unroll
    for (int mt = 0; mt < 2; ++mt) {
      int kg = (mt << 3) + ks;
      int u = (kg << 6) + (lane ^ (kg & 7));
      half8 ah = *(const half8*)&Ahi[u << 3];
      half8 al = *(const half8*)&Alo[u << 3];
      half8 arh = relu8(ah, ah);
      half8 arl = relu8(ah, al);
      #pragma unroll
      for (int nt = 0; nt < 2; ++nt) {
        hm[mt][nt] = __builtin_amdgcn_mfma_f32_16x16x32_f16(arh, c0h[nt], hm[mt][nt], 0, 0, 0);
        hc[mt][nt] = __builtin_amdgcn_mfma_f32_16x16x32_f16(arl, c0h[nt], hc[mt][nt], 0, 0, 0);
        hc[mt][nt] = __builtin_amdgcn_mfma_f32_16x16x32_f16(arh, c0l[nt], hc[mt][nt], 0, 0, 0);
        so[mt][nt] = __builtin_amdgcn_mfma_f32_16x16x32_f16(ah,  csh[nt], so[mt][nt], 0, 0, 0);
        sc[mt][nt] = __builtin_amdgcn_mfma_f32_16x16x32_f16(al,  csh[nt], sc[mt][nt], 0, 0, 0);
        sc[mt][nt] = __builtin_amdgcn_mfma_f32_16x16x32_f16(ah,  csl[nt], sc[mt][nt], 0, 0, 0);
      }
    }
    #pragma unroll
    for (int nt = 0; nt < 2; ++nt) {
      c0h[nt] = n0h[nt]; c0l[nt] = n0l[nt];
      csh[nt] = nsh[nt]; csl[nt] = nsl[nt];
    }
  }
  __syncthreads();   // x planes dead; overlay h frags

  // ---- write relu(h) into A2 frag planes (K2 = 128) ----
  _Float16* A2hi = smem;                      // 4096 f16
  _Float16* A2lo = smem + 4096;
  {
    int q = lane >> 4, j2 = lane & 7, qh = (lane & 15) >> 3;
    #pragma unroll
    for (int mt = 0; mt < 2; ++mt) {
      int kg2 = (mt << 2) + wave;             // [0,8)
      #pragma unroll
      for (int nt = 0; nt < 2; ++nt) {
        int quad2 = (nt << 1) + qh;
        #pragma unroll
        for (int r = 0; r < 4; ++r) {
          float hv = fmaxf(fmaf(hc[mt][nt][r], INV4096, hm[mt][nt][r]), 0.f);
          _Float16 hb, lb; splith(hv, hb, lb);
          int mm2 = (q << 2) + r;
          int ln2 = mm2 + (quad2 << 4);
          int u2 = (kg2 << 6) + (ln2 ^ (kg2 & 7));
          A2hi[(u2 << 3) + j2] = hb;
          A2lo[(u2 << 3) + j2] = lb;
        }
      }
    }
  }
  __syncthreads();

  // ---- GEMM1: s += relu(h) @ w1 ----
  const _Float16* w1lo = w1p + 16384;
  half8 w1ch[2], w1cl[2];
  #pragma unroll
  for (int nt = 0; nt < 2; ++nt) {
    int tw = (wave << 1) + nt;
    size_t fo = (((size_t)(tw << 2) << 6) + lane) << 3;
    w1ch[nt] = *(const half8*)&w1p[fo];
    w1cl[nt] = *(const half8*)&w1lo[fo];
  }
  for (int ks = 0; ks < 4; ++ks) {
    half8 nh[2], nl[2];
    int ksn = (ks + 1) & 3;
    #pragma unroll
    for (int nt = 0; nt < 2; ++nt) {
      int tw = (wave << 1) + nt;
      size_t fo = (((size_t)((tw << 2) + ksn) << 6) + lane) << 3;
      nh[nt] = *(const half8*)&w1p[fo];
      nl[nt] = *(const half8*)&w1lo[fo];
    }
    #pragma unroll
    for (int mt = 0; mt < 2; ++mt) {
      int kg = (mt << 2) + ks;
      int u = (kg << 6) + (lane ^ (kg & 7));
      half8 ah = *(const half8*)&A2hi[u << 3];
      half8 al = *(const half8*)&A2lo[u << 3];
      #pragma unroll
      for (int nt = 0; nt < 2; ++nt) {
        so[mt][nt] = __builtin_amdgcn_mfma_f32_16x16x32_f16(ah, w1ch[nt], so[mt][nt], 0, 0, 0);
        sc[mt][nt] = __builtin_amdgcn_mfma_f32_16x16x32_f16(al, w1ch[nt], sc[mt][nt], 0, 0, 0);
        sc[mt][nt] = __builtin_amdgcn_mfma_f32_16x16x32_f16(ah, w1cl[nt], sc[mt][nt], 0, 0, 0);
      }
    }
    #pragma unroll
    for (int nt = 0; nt < 2; ++nt) { w1ch[nt] = nh[nt]; w1cl[nt] = nl[nt]; }
  }

  float* S = (float*)smem;                    // 32 x 132 f32 tile (16.9 KB)
  int* Bid = (int*)((char*)smem + 16896);     // 32 bin ids

  if (MODE == 0) {
    // ---- epilogue A: store net + fused segmented bin-max ----
    {
      int col = lane & 15, q = lane >> 4;
      #pragma unroll
      for (int mt = 0; mt < 2; ++mt) {
        #pragma unroll
        for (int r = 0; r < 4; ++r) {
          int m_g = p0 + (mt << 4) + (q << 2) + r;
          #pragma unroll
          for (int nt = 0; nt < 2; ++nt) {
            int n = (wave << 5) + (nt << 4) + col;
            net[(size_t)m_g * 128 + n] = fmaf(sc[mt][nt][r], INV4096, so[mt][nt][r]);
          }
        }
      }
    }
    __syncthreads();                          // all A2 reads done; reuse smem
    {
      int col = lane & 15, q = lane >> 4;
      #pragma unroll
      for (int mt = 0; mt < 2; ++mt) {
        #pragma unroll
        for (int r = 0; r < 4; ++r) {
          int mrow = (mt << 4) + (q << 2) + r;
          #pragma unroll
          for (int nt = 0; nt < 2; ++nt) {
            int n = (wave << 5) + (nt << 4) + col;
            S[mrow * 132 + n] = fmaf(sc[mt][nt][r], INV4096, so[mt][nt][r]);
          }
        }
      }
      if (tid < 32) Bid[tid] = sbin[p0 + tid];
    }
    __syncthreads();
    {
      int c = tid & 127, h = (tid >> 7) << 4;  // 16 rows per half, 128 channels
      int cur = Bid[h];
      unsigned acc = fenc(S[h * 132 + c]);
      #pragma unroll
      for (int m2 = 1; m2 < 16; ++m2) {
        int m = h + m2;
        int id = Bid[m];                       // uniform across the wave
        unsigned e = fenc(S[m * 132 + c]);
        if (id != cur) {
          atomicMax(&binsOut[(size_t)(((b << 14) + cur) << 7) + c], acc);
          cur = id; acc = e;
        } else if (e > acc) acc = e;
      }
      atomicMax(&binsOut[(size_t)(((b << 14) + cur) << 7) + c], acc);
    }
  } else {
    // ---- epilogue B: fused fc_c + segmented bin-sum (no net store) ----
    __syncthreads();                          // all A2 reads (GEMM1) done
    {
      int q = lane >> 4, j2 = lane & 7, qh = (lane & 15) >> 3;
      #pragma unroll
      for (int mt = 0; mt < 2; ++mt) {
        int kg2 = (mt << 2) + wave;
        #pragma unroll
        for (int nt = 0; nt < 2; ++nt) {
          int quad2 = (nt << 1) + qh;
          #pragma unroll
          for (int r = 0; r < 4; ++r) {
            float sv = fmaxf(fmaf(sc[mt][nt][r], INV4096, so[mt][nt][r]), 0.f);
            _Float16 hb, lb; splith(sv, hb, lb);
            int mm2 = (q << 2) + r;
            int ln2 = mm2 + (quad2 << 4);
            int u2 = (kg2 << 6) + (ln2 ^ (kg2 & 7));
            A2hi[(u2 << 3) + j2] = hb;
            A2lo[(u2 << 3) + j2] = lb;
          }
        }
      }
    }
    __syncthreads();
    const _Float16* flo = fccp + 16384;
    f32x4 am[2][2], ac[2][2];
    {
      int col = lane & 15;
      #pragma unroll
      for (int nt = 0; nt < 2; ++nt) {
        float bv = fccb[(wave << 5) + (nt << 4) + col];
        #pragma unroll
        for (int mt = 0; mt < 2; ++mt) {
          am[mt][nt] = (f32x4){bv, bv, bv, bv};
          ac[mt][nt] = (f32x4){0.f, 0.f, 0.f, 0.f};
        }
      }
    }
    for (int ks = 0; ks < 4; ++ks) {
      half8 ch[2], cl[2];
      #pragma unroll
      for (int nt = 0; nt < 2; ++nt) {
        int tw = (wave << 1) + nt;
        size_t fo = (((size_t)((tw << 2) + ks) << 6) + lane) << 3;
        ch[nt] = *(const half8*)&fccp[fo];
        cl[nt] = *(const half8*)&flo[fo];
      }
      #pragma unroll
      for (int mt = 0; mt < 2; ++mt) {
        int kg = (mt << 2) + ks;
        int u = (kg << 6) + (lane ^ (kg & 7));
        half8 ah = *(const half8*)&A2hi[u << 3];
        half8 al = *(const half8*)&A2lo[u << 3];
        #pragma unroll
        for (int nt = 0; nt < 2; ++nt) {
          am[mt][nt] = __builtin_amdgcn_mfma_f32_16x16x32_f16(ah, ch[nt], am[mt][nt], 0, 0, 0);
          ac[mt][nt] = __builtin_amdgcn_mfma_f32_16x16x32_f16(al, ch[nt], ac[mt][nt], 0, 0, 0);
          ac[mt][nt] = __builtin_amdgcn_mfma_f32_16x16x32_f16(ah, cl[nt], ac[mt][nt], 0, 0, 0);
        }
      }
    }
    __syncthreads();                          // all A2 reads done; reuse smem
    {
      int col = lane & 15, q = lane >> 4;
      #pragma unroll
      for (int mt = 0; mt < 2; ++mt) {
        #pragma unroll
        for (int r = 0; r < 4; ++r) {
          int mrow = (mt << 4) + (q << 2) + r;
          #pragma unroll
          for (int nt = 0; nt < 2; ++nt) {
            int n = (wave << 5) + (nt << 4) + col;
            S[mrow * 132 + n] = fmaf(ac[mt][nt][r], INV4096, am[mt][nt][r]);
          }
        }
      }
      if (tid < 32) Bid[tid] = sbin[p0 + tid];
    }
    __syncthreads();
    {
      int c = tid & 127, h = (tid >> 7) << 4;
      int cur = Bid[h];
      float acc = S[h * 132 + c];
      #pragma unroll
      for (int m2 = 1; m2 < 16; ++m2) {
        int m = h + m2;
        int id = Bid[m];
        float e = S[m * 132 + c];
        if (id != cur) {
          atomicAdd(&sums[(size_t)(((b << 14) + cur) << 7) + c], acc);
          cur = id; acc = e;
        } else acc += e;
      }
      atomicAdd(&sums[(size_t)(((b << 14) + cur) << 7) + c], acc);
    }
  }
}

// ---------- divide by counts + transpose (B,R2,C) -> (B,C,R2) ----------
__launch_bounds__(256)
__global__ void k_finalize(const float* __restrict__ sums, const int* __restrict__ cnti,
                           float* __restrict__ out) {
  __shared__ float t[64 * 65];
  __shared__ float rc[64];
  const int bid = blockIdx.x;
  const int ct = bid & 1, rt = (bid >> 1) & 255, b = bid >> 9;
  const int r0 = rt << 6, c0 = ct << 6;
  const int tid = threadIdx.x, l16 = tid & 15, sl = tid >> 4;
  for (int rr = sl; rr < 64; rr += 16) {
    float4 v = *(const float4*)&sums[(size_t)((b << 14) + r0 + rr) * 128 + c0 + (l16 << 2)];
    int cb = l16 << 2;
    t[rr * 65 + cb + 0] = v.x; t[rr * 65 + cb + 1] = v.y;
    t[rr * 65 + cb + 2] = v.z; t[rr * 65 + cb + 3] = v.w;
  }
  if (tid < 64) rc[tid] = 1.f / fmaxf((float)cnti[(b << 14) + r0 + tid], 1.f);
  __syncthreads();
  for (int cc = sl; cc < 64; cc += 16) {
    int c = c0 + cc;
    int rb = l16 << 2;
    float4 o = make_float4(t[(rb + 0) * 65 + cc] * rc[rb + 0],
                           t[(rb + 1) * 65 + cc] * rc[rb + 1],
                           t[(rb + 2) * 65 + cc] * rc[rb + 2],
                           t[(rb + 3) * 65 + cc] * rc[rb + 3]);
    *(float4*)&out[(size_t)((b << 7) + c) * 16384 + r0 + rb] = o;
  }
}

// ---------- host launch ----------
extern "C" void kernel_launch(void* const* d_in, const int* in_sizes, int n_in,
                              void* d_out, int out_size, void* d_ws, size_t ws_size,
                              hipStream_t stream) {
  const float* points = (const float*)d_in[0];
  const float* posw   = (const float*)d_in[1];
  const float* posb   = (const float*)d_in[2];
  const float* fc0w   = (const float*)d_in[3];
  const float* fc0b   = (const float*)d_in[4];
  const float* fc1w   = (const float*)d_in[5];
  const float* fc1b   = (const float*)d_in[6];
  const float* scw    = (const float*)d_in[7];
  const float* fccw   = (const float*)d_in[8];
  const float* fccb   = (const float*)d_in[9];
  float* outp = (float*)d_out;

  // workspace: net 32MB | bins0 32MB | bins1 32MB | sort | packed weights  (~103 MB)
  float* net      = (float*)d_ws;
  unsigned* bins0 = (unsigned*)(net + (size_t)BN * 128);
  unsigned* bins1 = bins0 + (size_t)BN * 128;
  int* perm   = (int*)(bins1 + (size_t)BN * 128);
  int* sbin   = perm + BN;
  int* cnti   = sbin + BN;
  int* cursor = cnti + BN;
  _Float16* wp = (_Float16*)(cursor + BN);

  const _Float16* w0_ = wp;            // 5 x 65536 (hi|lo)
  const _Float16* ws_ = wp + 327680;   // 5 x 65536
  const _Float16* w1_ = wp + 655360;   // 5 x 32768
  const _Float16* fcc_ = wp + 819200;  // 32768

  k_zero4<<<64, 256, 0, stream>>>((float4*)cnti, 16384);
  k_idx<<<256, 256, 0, stream>>>(points, cnti);
  k_scan<<<4, 256, 0, stream>>>(cnti, cursor);
  k_scatter<<<256, 256, 0, stream>>>(points, cursor, perm, sbin);
  k_pack<<<208, 256, 0, stream>>>(fc0w, scw, fc1w, fccw, wp);

  // layer 0: pool -> bins0
  k_zero4<<<8192, 256, 0, stream>>>((float4*)bins0, 2097152);
  k_rb<0, 0><<<2048, 256, 32768, stream>>>(points, nullptr, perm, sbin, posw, posb,
                                           w0_, fc0b, w1_, fc1b, ws_, net,
                                           bins0, fcc_, fccb, nullptr);
  unsigned* bin_in = bins0;
  unsigned* bin_out = bins1;
  // layers 1..3: read bin_in, pool -> bin_out
  for (int l = 1; l < 4; ++l) {
    k_zero4<<<8192, 256, 0, stream>>>((float4*)bin_out, 2097152);
    k_rb<1, 0><<<2048, 256, 32768, stream>>>(points, bin_in, perm, sbin, posw, posb,
                                             w0_ + (size_t)l * 65536, fc0b + l * 128,
                                             w1_ + (size_t)l * 32768, fc1b + l * 128,
                                             ws_ + (size_t)l * 65536, net,
                                             bin_out, fcc_, fccb, nullptr);
    unsigned* tsw = bin_in; bin_in = bin_out; bin_out = tsw;
  }
  // layer 4: read bin_in (=bins1), fused fc_c + scatter-mean sums -> bin_out (=bins0)
  float* sums = (float*)bin_out;
  k_zero4<<<8192, 256, 0, stream>>>((float4*)sums, 2097152);
  k_rb<1, 1><<<2048, 256, 32768, stream>>>(points, bin_in, perm, sbin, posw, posb,
                                           w0_ + (size_t)4 * 65536, fc0b + 4 * 128,
                                           w1_ + (size_t)4 * 32768, fc1b + 4 * 128,
                                           ws_ + (size_t)4 * 65536, net,
                                           nullptr, fcc_, fccb, sums);
  k_finalize<<<2048, 256, 0, stream>>>(sums, cnti, outp);
}

// Round 9
// 365.595 us; speedup vs baseline: 4.2264x; 1.1778x over previous
//
#include <hip/hip_runtime.h>

#define NBATCH 4
#define NPTS   16384
#define BN     (NBATCH * NPTS)   // 65536 points

typedef __attribute__((ext_vector_type(8))) _Float16 half8;
typedef __attribute__((ext_vector_type(4))) float f32x4;

#define INV4096 2.44140625e-4f

// ---------- split-fp16 (hi + lo*2^-12 ~ fp32 accuracy) ----------
__device__ __forceinline__ void splith(float x, _Float16& h, _Float16& l) {
  float ax = __builtin_fabsf(x);
  if (ax < 6.1035e-5f) {
    unsigned short sb = (unsigned short)((__float_as_uint(x) >> 16) & 0x8000u);
    h = __builtin_bit_cast(_Float16, sb);          // +/-0 preserves sign for relu
    l = (_Float16)(x * 4096.f);
  } else {
    _Float16 hh = (_Float16)x;
    h = hh;
    l = (_Float16)((x - (float)hh) * 4096.f);      // x-hh exact (Sterbenz)
  }
}
__device__ __forceinline__ void splith8(const float v[8], half8& hi, half8& lo) {
  #pragma unroll
  for (int j = 0; j < 8; ++j) { _Float16 h, l; splith(v[j], h, l); hi[j] = h; lo[j] = l; }
}

// zero halves of v where the corresponding half of sgn has its sign bit set
__device__ __forceinline__ half8 relu8(half8 sgn, half8 v) {
  uint4 s = __builtin_bit_cast(uint4, sgn);
  uint4 x = __builtin_bit_cast(uint4, v);
  unsigned* sp = (unsigned*)&s;
  unsigned* xp = (unsigned*)&x;
  uint4 out;
  unsigned* op = (unsigned*)&out;
  #pragma unroll
  for (int w = 0; w < 4; ++w) {
    unsigned m = sp[w] & 0x80008000u;
    unsigned drop = (m - (m >> 15)) | m;   // 0xFFFF per negative half
    op[w] = xp[w] & ~drop;
  }
  return __builtin_bit_cast(half8, out);
}

// ---------- utility kernels ----------
__global__ void k_zero4(float4* __restrict__ p, int n4) {
  int g = blockIdx.x * 256 + threadIdx.x;
  if (g < n4) p[g] = make_float4(0.f, 0.f, 0.f, 0.f);
}

__device__ __forceinline__ int bin_of(const float* __restrict__ pts, int g) {
  float px = pts[g * 3 + 0], py = pts[g * 3 + 1];
  int xi = (int)(px * 128.f); xi = xi < 0 ? 0 : (xi > 127 ? 127 : xi);
  int yi = (int)(py * 128.f); yi = yi < 0 ? 0 : (yi > 127 ? 127 : yi);
  return xi + (yi << 7);
}

__global__ void k_idx(const float* __restrict__ pts, int* __restrict__ cnti) {
  int g = blockIdx.x * 256 + threadIdx.x;
  if (g >= BN) return;
  int b = g >> 14;
  atomicAdd(&cnti[(b << 14) + bin_of(pts, g)], 1);
}

// per-batch exclusive scan of cnti -> off (sorted start) and cursor
__global__ void k_scan(const int* __restrict__ cnti, int* __restrict__ off,
                       int* __restrict__ cursor) {
  __shared__ int part[256];
  const int b = blockIdx.x, t = threadIdx.x;
  const int base = b << 14;
  int s = 0;
  #pragma unroll 8
  for (int i = 0; i < 64; ++i) s += cnti[base + t * 64 + i];
  part[t] = s;
  __syncthreads();
  for (int o = 1; o < 256; o <<= 1) {
    int v = (t >= o) ? part[t - o] : 0;
    __syncthreads();
    part[t] += v;
    __syncthreads();
  }
  int run = base + (t == 0 ? 0 : part[t - 1]);
  #pragma unroll 8
  for (int i = 0; i < 64; ++i) {
    int g = base + t * 64 + i;
    off[g] = run;
    cursor[g] = run;
    run += cnti[g];
  }
}

__global__ void k_scatter(const float* __restrict__ pts, int* __restrict__ cursor,
                          int* __restrict__ perm, int* __restrict__ sbin) {
  int p = blockIdx.x * 256 + threadIdx.x;
  if (p >= BN) return;
  int b = p >> 14;
  int id = bin_of(pts, p);
  int pos = atomicAdd(&cursor[(b << 14) + id], 1);
  perm[pos] = p;
  sbin[pos] = id;
}

// ---------- pack weights into frag-ordered split-fp16 planes ----------
__device__ __forceinline__ void pack_slot(const float* __restrict__ src, int K,
                                          _Float16* __restrict__ dhi, int NK,
                                          int slot) {
  int fpt = (K >> 5) << 6;
  int t = slot / fpt, rem = slot - t * fpt;
  int s = rem >> 6, lane = rem & 63;
  int row = (t << 4) + (lane & 15);
  int k0 = (s << 5) + ((lane >> 4) << 3);
  float v[8];
  #pragma unroll
  for (int j = 0; j < 8; ++j) v[j] = src[row * K + k0 + j];
  half8 hi, lo; splith8(v, hi, lo);
  *(half8*)&dhi[(size_t)slot << 3] = hi;
  *(half8*)&dhi[((size_t)slot << 3) + NK] = lo;
}

__global__ void k_pack(const float* __restrict__ fc0w, const float* __restrict__ scw,
                       const float* __restrict__ fc1w, const float* __restrict__ fccw,
                       _Float16* __restrict__ wp) {
  int g = blockIdx.x * 256 + threadIdx.x;
  if (g < 20480) {
    int l = g >> 12, slot = g & 4095;
    pack_slot(fc0w + (size_t)l * 32768, 256, wp + (size_t)l * 65536, 32768, slot);
  } else if (g < 40960) {
    int g2 = g - 20480; int l = g2 >> 12, slot = g2 & 4095;
    pack_slot(scw + (size_t)l * 32768, 256, wp + 327680 + (size_t)l * 65536, 32768, slot);
  } else if (g < 51200) {
    int g2 = g - 40960; int l = g2 >> 11, slot = g2 & 2047;
    pack_slot(fc1w + (size_t)l * 16384, 128, wp + 655360 + (size_t)l * 32768, 16384, slot);
  } else {
    int slot = g - 51200;
    pack_slot(fccw, 128, wp + 819200, 16384, slot);
  }
}

// ---------- fused ResnetBlockFC (MFMA, split-fp16), 32 sorted pts/block ----------
// Pooling is done ON READ: gather = segmented max over the bin's contiguous rows
// of netIn (previous layer output, ping-pong buffer). No bins array, no atomics.
// MODE 0: epilogue = plain store to netOut
// MODE 1: epilogue = fused fc_c GEMM + per-block segmented bin-sum -> atomicAdd(sums)
template <int SRC, int MODE>
__launch_bounds__(256, 4)
__global__ void k_rb(const float* __restrict__ pts, const float* __restrict__ netIn,
                     const int* __restrict__ perm, const int* __restrict__ sbin,
                     const int* __restrict__ off_, const int* __restrict__ cnti_,
                     const float* __restrict__ posw, const float* __restrict__ posb,
                     const _Float16* __restrict__ w0p, const float* __restrict__ b0,
                     const _Float16* __restrict__ w1p, const float* __restrict__ b1,
                     const _Float16* __restrict__ wsp,
                     float* __restrict__ netOut,
                     const _Float16* __restrict__ fccp, const float* __restrict__ fccb,
                     float* __restrict__ sums) {
  extern __shared__ _Float16 smem[];          // 32 KB
  _Float16* Ahi = smem;                       // 8192 f16
  _Float16* Alo = smem + 8192;
  const int tid = threadIdx.x;
  const int lane = tid & 63, wave = tid >> 6;
  const int p0 = blockIdx.x << 5;             // 32 sorted points
  const int b = p0 >> 14;

  // ---- stage x (hi/lo frag planes, XOR-swizzled); gather half = pooled max ----
  #pragma unroll
  for (int i = 0; i < 4; ++i) {
    int sidx = tid + (i << 8);                // 1024 slots
    int m = sidx >> 5, kslot = sidx & 31, k0 = kslot << 3;
    float v[8];
    if (SRC == 0) {
      const float* pp = &pts[(size_t)perm[p0 + m] * 3];
      float px = pp[0], py = pp[1], pz = pp[2];
      #pragma unroll
      for (int j = 0; j < 8; ++j) {
        int c = k0 + j;
        v[j] = fmaf(posw[c * 3 + 0], px,
               fmaf(posw[c * 3 + 1], py,
               fmaf(posw[c * 3 + 2], pz, posb[c])));
      }
    } else {
      if (kslot < 16) {
        float4 a = *(const float4*)&netIn[(size_t)(p0 + m) * 128 + k0];
        float4 c = *(const float4*)&netIn[(size_t)(p0 + m) * 128 + k0 + 4];
        v[0] = a.x; v[1] = a.y; v[2] = a.z; v[3] = a.w;
        v[4] = c.x; v[5] = c.y; v[6] = c.z; v[7] = c.w;
      } else {
        // pooled features: max over this bin's contiguous sorted rows (n >= 1)
        int g = (b << 14) + sbin[p0 + m];
        int s0 = off_[g], n = cnti_[g];
        const float* base = &netIn[(size_t)s0 * 128 + (k0 - 128)];
        float4 a = *(const float4*)base;
        float4 c = *(const float4*)(base + 4);
        for (int r = 1; r < n; ++r) {
          const float* rp = base + (size_t)r * 128;
          float4 va = *(const float4*)rp;
          float4 vc = *(const float4*)(rp + 4);
          a.x = fmaxf(a.x, va.x); a.y = fmaxf(a.y, va.y);
          a.z = fmaxf(a.z, va.z); a.w = fmaxf(a.w, va.w);
          c.x = fmaxf(c.x, vc.x); c.y = fmaxf(c.y, vc.y);
          c.z = fmaxf(c.z, vc.z); c.w = fmaxf(c.w, vc.w);
        }
        v[0] = a.x; v[1] = a.y; v[2] = a.z; v[3] = a.w;
        v[4] = c.x; v[5] = c.y; v[6] = c.z; v[7] = c.w;
      }
    }
    half8 hi, lo; splith8(v, hi, lo);
    int mt = m >> 4, mm = m & 15, s = kslot >> 2, quad = kslot & 3;
    int ln = mm + (quad << 4), kg = (mt << 3) + s;   // kg in [0,16)
    int u = (kg << 6) + (ln ^ (kg & 7));
    *(half8*)&Ahi[u << 3] = hi;
    *(half8*)&Alo[u << 3] = lo;
  }
  __syncthreads();

  // ---- combined K-loop: h = relu(x)@w0+b0 ; s = x@ws+b1 (main + cross acc) ----
  f32x4 hm[2][2], hc[2][2], so[2][2], sc[2][2];
  {
    int col = lane & 15;
    #pragma unroll
    for (int nt = 0; nt < 2; ++nt) {
      float bv0 = b0[(wave << 5) + (nt << 4) + col];
      float bv1 = b1[(wave << 5) + (nt << 4) + col];
      #pragma unroll
      for (int mt = 0; mt < 2; ++mt) {
        hm[mt][nt] = (f32x4){bv0, bv0, bv0, bv0};
        so[mt][nt] = (f32x4){bv1, bv1, bv1, bv1};
        hc[mt][nt] = (f32x4){0.f, 0.f, 0.f, 0.f};
        sc[mt][nt] = (f32x4){0.f, 0.f, 0.f, 0.f};
      }
    }
  }
  const _Float16* w0lo = w0p + 32768;
  const _Float16* wslo = wsp + 32768;

  half8 c0h[2], c0l[2], csh[2], csl[2];
  #pragma unroll
  for (int nt = 0; nt < 2; ++nt) {            // preload ks = 0
    int tw = (wave << 1) + nt;
    size_t fo = (((size_t)(tw << 3) << 6) + lane) << 3;
    c0h[nt] = *(const half8*)&w0p[fo];
    c0l[nt] = *(const half8*)&w0lo[fo];
    csh[nt] = *(const half8*)&wsp[fo];
    csl[nt] = *(const half8*)&wslo[fo];
  }
  #pragma unroll
  for (int ks = 0; ks < 8; ++ks) {
    half8 n0h[2], n0l[2], nsh[2], nsl[2];
    if (ks < 7) {
      #pragma unroll
      for (int nt = 0; nt < 2; ++nt) {
        int tw = (wave << 1) + nt;
        size_t fo = (((size_t)((tw << 3) + ks + 1) << 6) + lane) << 3;
        n0h[nt] = *(const half8*)&w0p[fo];
        n0l[nt] = *(const half8*)&w0lo[fo];
        nsh[nt] = *(const half8*)&wsp[fo];
        nsl[nt] = *(const half8*)&wslo[fo];
      }
    }
    #pragma unroll
    for (int mt = 0; mt < 2; ++mt) {
      int kg = (mt << 3) + ks;
      int u = (kg << 6) + (lane ^ (kg & 7));
      half8 ah = *(const half8*)&Ahi[u << 3];
      half8 al = *(const half8*)&Alo[u << 3];
      half8 arh = relu8(ah, ah);
      half8 arl = relu8(ah, al);
      #pragma unroll
      for (int nt = 0; nt < 2; ++nt) {
        hm[mt][nt] = __builtin_amdgcn_mfma_f32_16x16x32_f16(arh, c0h[nt], hm[mt][nt], 0, 0, 0);
        hc[mt][nt] = __builtin_amdgcn_mfma_f32_16x16x32_f16(arl, c0h[nt], hc[mt][nt], 0, 0, 0);
        hc[mt][nt] = __builtin_amdgcn_mfma_f32_16x16x32_f16(arh, c0l[nt], hc[mt][nt], 0, 0, 0);
        so[mt][nt] = __builtin_amdgcn_mfma_f32_16x16x32_f16(ah,  csh[nt], so[mt][nt], 0, 0, 0);
        sc[mt][nt] = __builtin_amdgcn_mfma_f32_16x16x32_f16(al,  csh[nt], sc[mt][nt], 0, 0, 0);
        sc[mt][nt] = __builtin_amdgcn_mfma_f32_16x16x32_f16(ah,  csl[nt], sc[mt][nt], 0, 0, 0);
      }
    }
    if (ks < 7) {
      #pragma unroll
      for (int nt = 0; nt < 2; ++nt) {
        c0h[nt] = n0h[nt]; c0l[nt] = n0l[nt];
        csh[nt] = nsh[nt]; csl[nt] = nsl[nt];
      }
    }
  }
  __syncthreads();   // x planes dead; overlay h frags

  // ---- write relu(h) into A2 frag planes (K2 = 128) ----
  _Float16* A2hi = smem;                      // 4096 f16
  _Float16* A2lo = smem + 4096;
  {
    int q = lane >> 4, j2 = lane & 7, qh = (lane & 15) >> 3;
    #pragma unroll
    for (int mt = 0; mt < 2; ++mt) {
      int kg2 = (mt << 2) + wave;             // [0,8)
      #pragma unroll
      for (int nt = 0; nt < 2; ++nt) {
        int quad2 = (nt << 1) + qh;
        #pragma unroll
        for (int r = 0; r < 4; ++r) {
          float hv = fmaxf(fmaf(hc[mt][nt][r], INV4096, hm[mt][nt][r]), 0.f);
          _Float16 hb, lb; splith(hv, hb, lb);
          int mm2 = (q << 2) + r;
          int ln2 = mm2 + (quad2 << 4);
          int u2 = (kg2 << 6) + (ln2 ^ (kg2 & 7));
          A2hi[(u2 << 3) + j2] = hb;
          A2lo[(u2 << 3) + j2] = lb;
        }
      }
    }
  }
  __syncthreads();

  // ---- GEMM1: s += relu(h) @ w1 ----
  const _Float16* w1lo = w1p + 16384;
  half8 w1ch[2], w1cl[2];
  #pragma unroll
  for (int nt = 0; nt < 2; ++nt) {
    int tw = (wave << 1) + nt;
    size_t fo = (((size_t)(tw << 2) << 6) + lane) << 3;
    w1ch[nt] = *(const half8*)&w1p[fo];
    w1cl[nt] = *(const half8*)&w1lo[fo];
  }
  #pragma unroll
  for (int ks = 0; ks < 4; ++ks) {
    half8 nh[2], nl[2];
    if (ks < 3) {
      #pragma unroll
      for (int nt = 0; nt < 2; ++nt) {
        int tw = (wave << 1) + nt;
        size_t fo = (((size_t)((tw << 2) + ks + 1) << 6) + lane) << 3;
        nh[nt] = *(const half8*)&w1p[fo];
        nl[nt] = *(const half8*)&w1lo[fo];
      }
    }
    #pragma unroll
    for (int mt = 0; mt < 2; ++mt) {
      int kg = (mt << 2) + ks;
      int u = (kg << 6) + (lane ^ (kg & 7));
      half8 ah = *(const half8*)&A2hi[u << 3];
      half8 al = *(const half8*)&A2lo[u << 3];
      #pragma unroll
      for (int nt = 0; nt < 2; ++nt) {
        so[mt][nt] = __builtin_amdgcn_mfma_f32_16x16x32_f16(ah, w1ch[nt], so[mt][nt], 0, 0, 0);
        sc[mt][nt] = __builtin_amdgcn_mfma_f32_16x16x32_f16(al, w1ch[nt], sc[mt][nt], 0, 0, 0);
        sc[mt][nt] = __builtin_amdgcn_mfma_f32_16x16x32_f16(ah, w1cl[nt], sc[mt][nt], 0, 0, 0);
      }
    }
    if (ks < 3) {
      #pragma unroll
      for (int nt = 0; nt < 2; ++nt) { w1ch[nt] = nh[nt]; w1cl[nt] = nl[nt]; }
    }
  }

  if (MODE == 0) {
    // ---- epilogue A: plain store to netOut (sorted rows) ----
    int col = lane & 15, q = lane >> 4;
    #pragma unroll
    for (int mt = 0; mt < 2; ++mt) {
      #pragma unroll
      for (int r = 0; r < 4; ++r) {
        int m_g = p0 + (mt << 4) + (q << 2) + r;
        #pragma unroll
        for (int nt = 0; nt < 2; ++nt) {
          int n = (wave << 5) + (nt << 4) + col;
          netOut[(size_t)m_g * 128 + n] = fmaf(sc[mt][nt][r], INV4096, so[mt][nt][r]);
        }
      }
    }
  } else {
    // ---- epilogue B: fused fc_c + segmented bin-sum ----
    float* S = (float*)smem;                    // 32 x 132 f32 tile (16.9 KB)
    int* Bid = (int*)((char*)smem + 16896);     // 32 bin ids
    __syncthreads();                          // all A2 reads (GEMM1) done
    {
      int q = lane >> 4, j2 = lane & 7, qh = (lane & 15) >> 3;
      #pragma unroll
      for (int mt = 0; mt < 2; ++mt) {
        int kg2 = (mt << 2) + wave;
        #pragma unroll
        for (int nt = 0; nt < 2; ++nt) {
          int quad2 = (nt << 1) + qh;
          #pragma unroll
          for (int r = 0; r < 4; ++r) {
            float sv = fmaxf(fmaf(sc[mt][nt][r], INV4096, so[mt][nt][r]), 0.f);
            _Float16 hb, lb; splith(sv, hb, lb);
            int mm2 = (q << 2) + r;
            int ln2 = mm2 + (quad2 << 4);
            int u2 = (kg2 << 6) + (ln2 ^ (kg2 & 7));
            A2hi[(u2 << 3) + j2] = hb;
            A2lo[(u2 << 3) + j2] = lb;
          }
        }
      }
    }
    __syncthreads();
    const _Float16* flo = fccp + 16384;
    f32x4 am[2][2], ac[2][2];
    {
      int col = lane & 15;
      #pragma unroll
      for (int nt = 0; nt < 2; ++nt) {
        float bv = fccb[(wave << 5) + (nt << 4) + col];
        #pragma unroll
        for (int mt = 0; mt < 2; ++mt) {
          am[mt][nt] = (f32x4){bv, bv, bv, bv};
          ac[mt][nt] = (f32x4){0.f, 0.f, 0.f, 0.f};
        }
      }
    }
    #pragma unroll
    for (int ks = 0; ks < 4; ++ks) {
      half8 ch[2], cl[2];
      #pragma unroll
      for (int nt = 0; nt < 2; ++nt) {
        int tw = (wave << 1) + nt;
        size_t fo = (((size_t)((tw << 2) + ks) << 6) + lane) << 3;
        ch[nt] = *(const half8*)&fccp[fo];
        cl[nt] = *(const half8*)&flo[fo];
      }
      #pragma unroll
      for (int mt = 0; mt < 2; ++mt) {
        int kg = (mt << 2) + ks;
        int u = (kg << 6) + (lane ^ (kg & 7));
        half8 ah = *(const half8*)&A2hi[u << 3];
        half8 al = *(const half8*)&A2lo[u << 3];
        #pragma unroll
        for (int nt = 0; nt < 2; ++nt) {
          am[mt][nt] = __builtin_amdgcn_mfma_f32_16x16x32_f16(ah, ch[nt], am[mt][nt], 0, 0, 0);
          ac[mt][nt] = __builtin_amdgcn_mfma_f32_16x16x32_f16(al, ch[nt], ac[mt][nt], 0, 0, 0);
          ac[mt][nt] = __builtin_amdgcn_mfma_f32_16x16x32_f16(ah, cl[nt], ac[mt][nt], 0, 0, 0);
        }
      }
    }
    __syncthreads();                          // all A2 reads done; reuse smem
    {
      int col = lane & 15, q = lane >> 4;
      #pragma unroll
      for (int mt = 0; mt < 2; ++mt) {
        #pragma unroll
        for (int r = 0; r < 4; ++r) {
          int mrow = (mt << 4) + (q << 2) + r;
          #pragma unroll
          for (int nt = 0; nt < 2; ++nt) {
            int n = (wave << 5) + (nt << 4) + col;
            S[mrow * 132 + n] = fmaf(ac[mt][nt][r], INV4096, am[mt][nt][r]);
          }
        }
      }
      if (tid < 32) Bid[tid] = sbin[p0 + tid];
    }
    __syncthreads();
    {
      int c = tid & 127, h = (tid >> 7) << 4;
      int cur = Bid[h];
      float acc = S[h * 132 + c];
      #pragma unroll
      for (int m2 = 1; m2 < 16; ++m2) {
        int m = h + m2;
        int id = Bid[m];
        float e = S[m * 132 + c];
        if (id != cur) {
          atomicAdd(&sums[(size_t)(((b << 14) + cur) << 7) + c], acc);
          cur = id; acc = e;
        } else acc += e;
      }
      atomicAdd(&sums[(size_t)(((b << 14) + cur) << 7) + c], acc);
    }
  }
}

// ---------- divide by counts + transpose (B,R2,C) -> (B,C,R2) ----------
__launch_bounds__(256)
__global__ void k_finalize(const float* __restrict__ sums, const int* __restrict__ cnti,
                           float* __restrict__ out) {
  __shared__ float t[64 * 65];
  __shared__ float rc[64];
  const int bid = blockIdx.x;
  const int ct = bid & 1, rt = (bid >> 1) & 255, b = bid >> 9;
  const int r0 = rt << 6, c0 = ct << 6;
  const int tid = threadIdx.x, l16 = tid & 15, sl = tid >> 4;
  for (int rr = sl; rr < 64; rr += 16) {
    float4 v = *(const float4*)&sums[(size_t)((b << 14) + r0 + rr) * 128 + c0 + (l16 << 2)];
    int cb = l16 << 2;
    t[rr * 65 + cb + 0] = v.x; t[rr * 65 + cb + 1] = v.y;
    t[rr * 65 + cb + 2] = v.z; t[rr * 65 + cb + 3] = v.w;
  }
  if (tid < 64) rc[tid] = 1.f / fmaxf((float)cnti[(b << 14) + r0 + tid], 1.f);
  __syncthreads();
  for (int cc = sl; cc < 64; cc += 16) {
    int c = c0 + cc;
    int rb = l16 << 2;
    float4 o = make_float4(t[(rb + 0) * 65 + cc] * rc[rb + 0],
                           t[(rb + 1) * 65 + cc] * rc[rb + 1],
                           t[(rb + 2) * 65 + cc] * rc[rb + 2],
                           t[(rb + 3) * 65 + cc] * rc[rb + 3]);
    *(float4*)&out[(size_t)((b << 7) + c) * 16384 + r0 + rb] = o;
  }
}

// ---------- host launch ----------
extern "C" void kernel_launch(void* const* d_in, const int* in_sizes, int n_in,
                              void* d_out, int out_size, void* d_ws, size_t ws_size,
                              hipStream_t stream) {
  const float* points = (const float*)d_in[0];
  const float* posw   = (const float*)d_in[1];
  const float* posb   = (const float*)d_in[2];
  const float* fc0w   = (const float*)d_in[3];
  const float* fc0b   = (const float*)d_in[4];
  const float* fc1w   = (const float*)d_in[5];
  const float* fc1b   = (const float*)d_in[6];
  const float* scw    = (const float*)d_in[7];
  const float* fccw   = (const float*)d_in[8];
  const float* fccb   = (const float*)d_in[9];
  float* outp = (float*)d_out;

  // workspace: net_a 32MB | net_b 32MB | sort | packed weights  (~70 MB)
  float* net_a = (float*)d_ws;
  float* net_b = net_a + (size_t)BN * 128;
  int* perm   = (int*)(net_b + (size_t)BN * 128);
  int* sbin   = perm + BN;
  int* cnti   = sbin + BN;
  int* off    = cnti + BN;
  int* cursor = off + BN;
  _Float16* wp = (_Float16*)(cursor + BN);

  const _Float16* w0_ = wp;            // 5 x 65536 (hi|lo)
  const _Float16* ws_ = wp + 327680;   // 5 x 65536
  const _Float16* w1_ = wp + 655360;   // 5 x 32768
  const _Float16* fcc_ = wp + 819200;  // 32768

  k_zero4<<<64, 256, 0, stream>>>((float4*)cnti, 16384);
  k_idx<<<256, 256, 0, stream>>>(points, cnti);
  k_scan<<<4, 256, 0, stream>>>(cnti, off, cursor);
  k_scatter<<<256, 256, 0, stream>>>(points, cursor, perm, sbin);
  k_pack<<<208, 256, 0, stream>>>(fc0w, scw, fc1w, fccw, wp);

  // ping-pong: L0 -> a, L1: a->b, L2: b->a, L3: a->b, L4: b -> sums(=a)
  k_rb<0, 0><<<2048, 256, 32768, stream>>>(points, nullptr, perm, sbin, off, cnti,
                                           posw, posb,
                                           w0_, fc0b, w1_, fc1b, ws_, net_a,
                                           fcc_, fccb, nullptr);
  const float* src = net_a;
  float* dst = net_b;
  for (int l = 1; l < 4; ++l) {
    k_rb<1, 0><<<2048, 256, 32768, stream>>>(points, src, perm, sbin, off, cnti,
                                             posw, posb,
                                             w0_ + (size_t)l * 65536, fc0b + l * 128,
                                             w1_ + (size_t)l * 32768, fc1b + l * 128,
                                             ws_ + (size_t)l * 65536, dst,
                                             fcc_, fccb, nullptr);
    float* t = (float*)src; src = dst; dst = t;
  }
  // after L3: src = net_b (L3 output), dst = net_a (dead) -> reuse as sums
  float* sums = dst;
  k_zero4<<<8192, 256, 0, stream>>>((float4*)sums, 2097152);
  k_rb<1, 1><<<2048, 256, 32768, stream>>>(points, src, perm, sbin, off, cnti,
                                           posw, posb,
                                           w0_ + (size_t)4 * 65536, fc0b + 4 * 128,
                                           w1_ + (size_t)4 * 32768, fc1b + 4 * 128,
                                           ws_ + (size_t)4 * 65536, nullptr,
                                           fcc_, fccb, sums);
  k_finalize<<<2048, 256, 0, stream>>>(sums, cnti, outp);
}